// Round 10
// baseline (463.958 us; speedup 1.0000x reference)
//
#include <hip/hip_runtime.h>
#include <hip/hip_bf16.h>

// ---------------------------------------------------------------------------
// SmallthinkerAttention: hs->QKV proj -> RoPE -> causal attn (writes P) -> out proj
// B=2 S=2048 HID=2048 NH=32 NKV=8 HD=64
// d_out = [out (2*2048*2048 f32), attn_weights (2*32*2048*2048 f32)]
// R10: GEMMs replaced with 256^2-tile 8-wave BK=32 kernel: triple-buffered LDS,
//      counted vmcnt(4) (T4, never 0 mid-loop), st_16x32 LDS swizzle applied
//      both-sides (pre-swizzled global source lane + swizzled ds_read, rule #21),
//      T1 XCD swizzle, setprio around MFMA. Attn unchanged from R9.
// ---------------------------------------------------------------------------

typedef __bf16 bf16;
typedef bf16 bf16x8 __attribute__((ext_vector_type(8)));
typedef bf16 bf16x4 __attribute__((ext_vector_type(4)));
typedef float f32x4 __attribute__((ext_vector_type(4)));

#define B_   2
#define S_   2048
#define HID_ 2048
#define NH_  32
#define NKV_ 8
#define HD_  64
#define TOK_ (B_*S_)          // 4096
#define QKVN 3072             // fused QKV output cols: 2048 q | 512 k | 512 v

// barrier WITHOUT the implicit vmcnt(0) drain
#define BAR_LGKM() do { asm volatile("s_waitcnt lgkmcnt(0)" ::: "memory"); \
                        __builtin_amdgcn_s_barrier(); } while (0)

// async global->LDS, 16B per lane, LDS dest = wave-uniform base + lane*16
__device__ __forceinline__ void gl_lds16(const bf16* g, bf16* l) {
  __builtin_amdgcn_global_load_lds(
      (const __attribute__((address_space(1))) unsigned int*)(g),
      (__attribute__((address_space(3))) unsigned int*)(l), 16, 0, 0);
}

// ---------------- cast f32 -> bf16 (vectorized) ----------------
__global__ __launch_bounds__(256) void cast_f32_bf16(const float* __restrict__ in,
                                                     bf16* __restrict__ out, int n4) {
  int i = blockIdx.x * 256 + threadIdx.x;
  if (i >= n4) return;
  f32x4 v = ((const f32x4*)in)[i];
  bf16x4 o;
  o[0] = (bf16)v[0]; o[1] = (bf16)v[1]; o[2] = (bf16)v[2]; o[3] = (bf16)v[3];
  ((bf16x4*)out)[i] = o;
}

// fused Wq|Wk|Wv cast into contiguous Wqkv (rows: 2048 q | 512 k | 512 v)
__global__ __launch_bounds__(256) void cast_wqkv(const float* __restrict__ wq,
                                                 const float* __restrict__ wk,
                                                 const float* __restrict__ wv,
                                                 bf16* __restrict__ dst) {
  int i = blockIdx.x * 256 + threadIdx.x;      // 0 .. 1572863 (x4 units)
  const float* src; int off;
  if (i < 1048576)      { src = wq; off = i; }
  else if (i < 1310720) { src = wk; off = i - 1048576; }
  else                  { src = wv; off = i - 1310720; }
  f32x4 v = ((const f32x4*)src)[off];
  bf16x4 o;
  o[0] = (bf16)v[0]; o[1] = (bf16)v[1]; o[2] = (bf16)v[2]; o[3] = (bf16)v[3];
  ((bf16x4*)dst)[i] = o;
}

// ---------------- GEMM 256^2: C[M,N] = A[M,K] @ B[N,K]^T ----------------
// 8 waves (2Mx4N), per-wave 128x64 output (8x4 frags of 16x16x32).
// Triple-buffered LDS (3 x (A 16KB + B 16KB) = 96KB), BK=32.
// Counted vmcnt: tiles staged 2 ahead, vmcnt(4) at boundaries (vmcnt(0) only
// when lookahead ends). st_16x32 swizzle: linear global_load_lds dest +
// source-lane perm (l>=32: l^2) + XOR'd ds_read offsets.
template<bool OUT_F32>
__global__ __launch_bounds__(512, 2) void gemm256(const bf16* __restrict__ A,
                                                  const bf16* __restrict__ Bm,
                                                  void* __restrict__ Cout,
                                                  int M, int N, int K) {
  __shared__ __align__(16) bf16 sA[3][256 * 32];
  __shared__ __align__(16) bf16 sB[3][256 * 32];
  const int tid  = threadIdx.x;
  const int wave = tid >> 6, lane = tid & 63;

  // T1 XCD-aware swizzle (nwg % 8 == 0 for all our launches)
  const int nwg = (int)(gridDim.x * gridDim.y);
  const int bid = (int)(blockIdx.y * gridDim.x + blockIdx.x);
  const int swz = (bid & 7) * (nwg >> 3) + (bid >> 3);
  const int bx = swz % (int)gridDim.x, by = swz / (int)gridDim.x;
  const int bm = by * 256, bn = bx * 256;

  const int wmi = wave >> 2, wni = wave & 3;   // wave -> (M half, N quarter)
  const int fr = lane & 15, fg = lane >> 4;

  // ---- staging: source-lane permutation realizes st_16x32 swizzle ----
  // lane's linear LDS byte off = wave*1024 + lane*16; bit9 = lane bit5, so
  // logical source lane l' = (l<32) ? l : l^2.
  const int lp = (lane < 32) ? lane : (lane ^ 2);
  const int tt = (wave << 6) | lp;
  const int srow = tt >> 2;                    // 0..127 within a 128-row half
  const int scol = (tt & 3) * 8;               // elems
  const bf16* gA = A  + (size_t)(bm + srow) * K + scol;
  const bf16* gB = Bm + (size_t)(bn + srow) * K + scol;
  bf16* ldA = &sA[0][0] + wave * 512;          // + buf*8192 + half*4096
  bf16* ldB = &sB[0][0] + wave * 512;

  // ---- swizzled ds_read element offsets (within one operand tile buffer) ----
  int aOff[8], bOff[4];
#pragma unroll
  for (int m = 0; m < 8; ++m) {
    int L = (m * 16 + fr) * 64 + fg * 16;      // logical byte off in half
    L ^= ((L >> 9) & 1) << 5;
    aOff[m] = wmi * 4096 + (L >> 1);
  }
#pragma unroll
  for (int n = 0; n < 4; ++n) {
    int rh = (wni & 1) * 64 + n * 16 + fr;
    int L = rh * 64 + fg * 16;
    L ^= ((L >> 9) & 1) << 5;
    bOff[n] = (wni >> 1) * 4096 + (L >> 1);
  }

  f32x4 acc[8][4] = {};
  const int NT = K >> 5;                       // K-tiles of 32

  // stage tile t into buffer buf (4 vm ops per wave)
  auto stage = [&](int t, int buf) {
    const bf16* ga = gA + (size_t)t * 32;
    const bf16* gb = gB + (size_t)t * 32;
    gl_lds16(ga,                   ldA + buf * 8192);
    gl_lds16(ga + (size_t)128 * K, ldA + buf * 8192 + 4096);
    gl_lds16(gb,                   ldB + buf * 8192);
    gl_lds16(gb + (size_t)128 * K, ldB + buf * 8192 + 4096);
  };

  // prologue: tiles 0,1 in flight; wait tile0 (4 newest remain outstanding)
  stage(0, 0);
  stage(1, 1);
  asm volatile("s_waitcnt vmcnt(4)" ::: "memory");
  __builtin_amdgcn_s_barrier();

  int ct = 0, st = 2;                          // compute buf, stage buf (t+2)
  for (int t = 0; t < NT; ++t) {
    if (t + 2 < NT) stage(t + 2, st);

    bf16x8 af[8], bfv[4];
#pragma unroll
    for (int m = 0; m < 8; ++m) af[m] = *(const bf16x8*)&sA[ct][aOff[m]];
#pragma unroll
    for (int n = 0; n < 4; ++n) bfv[n] = *(const bf16x8*)&sB[ct][bOff[n]];

    __builtin_amdgcn_s_setprio(1);
#pragma unroll
    for (int m = 0; m < 8; ++m)
#pragma unroll
      for (int n = 0; n < 4; ++n)
        acc[m][n] = __builtin_amdgcn_mfma_f32_16x16x32_bf16(af[m], bfv[n], acc[m][n], 0, 0, 0);
    __builtin_amdgcn_s_setprio(0);

    // counted boundary wait: next tile's 4 loads done, t+2's stay in flight
    if (t + 2 < NT)      asm volatile("s_waitcnt vmcnt(4)" ::: "memory");
    else if (t + 1 < NT) asm volatile("s_waitcnt vmcnt(0)" ::: "memory");
    __builtin_amdgcn_s_barrier();

    ct = (ct == 2) ? 0 : ct + 1;
    st = (st == 2) ? 0 : st + 1;
  }

  // epilogue: D layout col = fr, row = fg*4 + r
#pragma unroll
  for (int m = 0; m < 8; ++m)
#pragma unroll
    for (int n = 0; n < 4; ++n)
#pragma unroll
      for (int r = 0; r < 4; ++r) {
        int row = bm + wmi * 128 + m * 16 + fg * 4 + r;
        int col = bn + wni * 64 + n * 16 + fr;
        float v = acc[m][n][r];
        if (OUT_F32) ((float*)Cout)[(size_t)row * N + col] = v;
        else         ((bf16*)Cout)[(size_t)row * N + col] = (bf16)v;
      }
}

// ---------------- RoPE: one block per token, q (32 heads) + k (8 heads) ------
__global__ __launch_bounds__(256) void rope_fused(bf16* __restrict__ qkv,
                                                  const float* __restrict__ cosp,
                                                  const float* __restrict__ sinp) {
  const int t = blockIdx.x;                    // 0..TOK-1
  const int tid = threadIdx.x;
  const int d = tid & 31, g = tid >> 5;        // g 0..7
  const float c = cosp[t * 64 + d];
  const float s = sinp[t * 64 + d];
  bf16* row = qkv + (size_t)t * QKVN;
#pragma unroll
  for (int i = 0; i < 4; ++i) {
    bf16* p = row + (g + i * 8) * 64 + d;      // q heads
    float x1 = (float)p[0], x2 = (float)p[32];
    p[0]  = (bf16)(x1 * c - x2 * s);
    p[32] = (bf16)(x2 * c + x1 * s);
  }
  bf16* p = row + 2048 + g * 64 + d;           // k head
  float x1 = (float)p[0], x2 = (float)p[32];
  p[0]  = (bf16)(x1 * c - x2 * s);
  p[32] = (bf16)(x2 * c + x1 * s);
}

// ---------------- transpose V: qkv v-cols -> vT[(b*8+kv)][64][2048] ----------
__global__ __launch_bounds__(256) void transpose_v(const bf16* __restrict__ v,  // qkv + 2560
                                                   bf16* __restrict__ vT) {
  __shared__ __align__(16) bf16 t[64][72];
  const int bkv = blockIdx.y;
  const int b = bkv >> 3, kv = bkv & 7;
  const int s0 = blockIdx.x * 64;
  const int tid = threadIdx.x;
  const int r = tid >> 3, c = (tid & 7) * 8;
#pragma unroll
  for (int p = 0; p < 2; ++p) {
    int rr = r + p * 32;
    *(bf16x8*)&t[rr][c] = *(const bf16x8*)&v[(size_t)(b * S_ + s0 + rr) * QKVN + kv * 64 + c];
  }
  __syncthreads();
#pragma unroll
  for (int p = 0; p < 2; ++p) {
    int d = r + p * 32;
    bf16x8 o;
#pragma unroll
    for (int j = 0; j < 8; ++j) o[j] = t[c + j][d];
    *(bf16x8*)&vT[((size_t)bkv * 64 + d) * S_ + s0 + c] = o;
  }
}

// ---------------- fused causal attention (stripe-paired, 4 waves) ----------------
// (unchanged from R9: swapped QK^T, raw barriers, zero-fill first, K dbuf pass1)
__global__ __launch_bounds__(256, 4) void attn_kernel(const bf16* __restrict__ qkv, // (TOK, 3072)
                                                      const bf16* __restrict__ vT,  // (16,64,2048)
                                                      float* __restrict__ attnw,    // (64, S, S)
                                                      bf16* __restrict__ attn_out)  // (TOK, 2048)
{
  __shared__ __align__(16) bf16 Ks2[2][64][72];
  __shared__ __align__(16) bf16 Vs[64][72];
  __shared__ __align__(16) bf16 Ps[4][16][72];

  const int tid  = threadIdx.x;
  const int wave = tid >> 6, lane = tid & 63;
  const int qt = blockIdx.x;                   // 0..15
  const int bh = blockIdx.y;                   // 0..63
  const int b = bh >> 5, h = bh & 31, kv = h >> 2;
  const int qLo = qt * 64;                     // LO stripe base row
  const int qHi = (31 - qt) * 64;              // HI stripe base row
  const int NT  = 32 - qt;                     // K/V tiles staged (HI needs all)
  const int fr = lane & 15, fg = lane >> 4;
  const int rw = wave * 16;                    // wave's row base within stripe
  const int rt = rw + fg * 4;                  // attn_out row group
  const int thr = rw + fr;                     // lane's q-row within stripe (diag threshold)

  const int lr = tid >> 2;                     // 0..63
  const int lc = (tid & 3) * 16;               // 0,16,32,48
  const bf16* kbase = qkv + (size_t)(b * S_) * QKVN + 2048 + kv * 64;
  const bf16* vbase = vT + (size_t)(b * NKV_ + kv) * 64 * S_;
  const bf16* kst = kbase + (size_t)lr * QKVN + lc;   // + jt*64*QKVN
  const bf16* vst = vbase + (size_t)lr * S_ + lc;     // + jt*64

  // tile-0 K loads FIRST (in-order vmcnt: retire before the zero-fill stores)
  bf16x8 kr0 = *(const bf16x8*)(kst);
  bf16x8 kr1 = *(const bf16x8*)(kst + 8);

  // Q fragments for both stripes (K=64 -> 2 chunks of 32); used as MFMA B-operand.
  bf16x8 aqL[2], aqH[2];
  {
    const bf16* qp = qkv + (size_t)(b * S_ + qLo + rw + fr) * QKVN + h * 64 + fg * 8;
    aqL[0] = *(const bf16x8*)qp;  aqL[1] = *(const bf16x8*)(qp + 32);
    qp = qkv + (size_t)(b * S_ + qHi + rw + fr) * QKVN + h * 64 + fg * 8;
    aqH[0] = *(const bf16x8*)qp;  aqH[1] = *(const bf16x8*)(qp + 32);
  }

  // ---------- zero-fill masked regions (background NT stores) ----------
  {
    f32x4 z4 = {0.f, 0.f, 0.f, 0.f};
    const int zLo = (qt + 1) * 64;              // LO rows: cols [zLo, S)
    for (int rr = 0; rr < 16; ++rr) {
      size_t base = ((size_t)bh * S_ + qLo + rw + rr) * S_;
      for (int c = zLo + lane * 4; c < S_; c += 256)
        __builtin_nontemporal_store(z4, (f32x4*)&attnw[base + c]);
    }
    const int zHi = NT * 64;                    // HI rows: cols [zHi, S)
    for (int rr = 0; rr < 16; ++rr) {
      size_t base = ((size_t)bh * S_ + qHi + rw + rr) * S_;
      for (int c = zHi + lane * 4; c < S_; c += 256)
        __builtin_nontemporal_store(z4, (f32x4*)&attnw[base + c]);
    }
  }

  // ---------- pass 1: rowsums of exp(logit), K double-buffered ----------
  float rsL = 0.f, rsH = 0.f;                  // scalar: lane owns q-row fr
  {
    *(bf16x8*)&Ks2[0][lr][lc]     = kr0;
    *(bf16x8*)&Ks2[0][lr][lc + 8] = kr1;
    BAR_LGKM();
    for (int jt = 0; jt < NT; ++jt) {
      const int cur = jt & 1;
      if (jt + 1 < NT) {                        // prefetch next tile to regs
        const bf16* p = kst + (size_t)(jt + 1) * 64 * QKVN;
        kr0 = *(const bf16x8*)(p);
        kr1 = *(const bf16x8*)(p + 8);
      }
      // HI stripe (always active)
      {
        f32x4 acc[4] = {};
#pragma unroll
        for (int nn = 0; nn < 4; ++nn) {
          bf16x8 bk0 = *(const bf16x8*)&Ks2[cur][nn*16 + fr][fg*8];
          bf16x8 bk1 = *(const bf16x8*)&Ks2[cur][nn*16 + fr][32 + fg*8];
          acc[nn] = __builtin_amdgcn_mfma_f32_16x16x32_bf16(bk0, aqH[0], acc[nn], 0, 0, 0);
          acc[nn] = __builtin_amdgcn_mfma_f32_16x16x32_bf16(bk1, aqH[1], acc[nn], 0, 0, 0);
        }
        if (jt < NT - 1) {                      // fully unmasked
#pragma unroll
          for (int nn = 0; nn < 4; ++nn)
#pragma unroll
            for (int r = 0; r < 4; ++r) rsH += __expf(acc[nn][r] * 0.125f);
        } else {                                // HI diagonal tile: k <= q
#pragma unroll
          for (int nn = 0; nn < 4; ++nn)
#pragma unroll
            for (int r = 0; r < 4; ++r)
              if (nn * 16 + fg * 4 + r <= thr) rsH += __expf(acc[nn][r] * 0.125f);
        }
      }
      // LO stripe (active for jt <= qt; block-uniform)
      if (jt <= qt) {
        f32x4 acc[4] = {};
#pragma unroll
        for (int nn = 0; nn < 4; ++nn) {
          bf16x8 bk0 = *(const bf16x8*)&Ks2[cur][nn*16 + fr][fg*8];
          bf16x8 bk1 = *(const bf16x8*)&Ks2[cur][nn*16 + fr][32 + fg*8];
          acc[nn] = __builtin_amdgcn_mfma_f32_16x16x32_bf16(bk0, aqL[0], acc[nn], 0, 0, 0);
          acc[nn] = __builtin_amdgcn_mfma_f32_16x16x32_bf16(bk1, aqL[1], acc[nn], 0, 0, 0);
        }
        if (jt < qt) {
#pragma unroll
          for (int nn = 0; nn < 4; ++nn)
#pragma unroll
            for (int r = 0; r < 4; ++r) rsL += __expf(acc[nn][r] * 0.125f);
        } else {                                // LO diagonal tile
#pragma unroll
          for (int nn = 0; nn < 4; ++nn)
#pragma unroll
            for (int r = 0; r < 4; ++r)
              if (nn * 16 + fg * 4 + r <= thr) rsL += __expf(acc[nn][r] * 0.125f);
        }
      }
      if (jt + 1 < NT) {                        // stage next tile, ONE barrier
        *(bf16x8*)&Ks2[cur ^ 1][lr][lc]     = kr0;
        *(bf16x8*)&Ks2[cur ^ 1][lr][lc + 8] = kr1;
        BAR_LGKM();
      }
    }
  }
  // reduce across the 4 fg lane-groups (k-partitions), then invert
  {
    float v = rsL;
    v += __shfl_xor(v, 16); v += __shfl_xor(v, 32);
    rsL = 1.0f / v;
    v = rsH;
    v += __shfl_xor(v, 16); v += __shfl_xor(v, 32);
    rsH = 1.0f / v;
  }

  // ---------- pass 2: recompute (swapped), write P f32x4, accumulate O ----------
  f32x4 oL[4] = {}, oH[4] = {};
  {
    float* awpL = attnw + ((size_t)bh * S_ + qLo + rw + fr) * S_;   // lane's LO row
    float* awpH = attnw + ((size_t)bh * S_ + qHi + rw + fr) * S_;   // lane's HI row
    const int cb = fg * 4;                      // lane's 4-col base within 16-window
    kr0 = *(const bf16x8*)(kst);               // prefetch tile 0
    kr1 = *(const bf16x8*)(kst + 8);
    bf16x8 vr0 = *(const bf16x8*)(vst);
    bf16x8 vr1 = *(const bf16x8*)(vst + 8);
    for (int jt = 0; jt < NT; ++jt) {
      const int j0 = jt * 64;
      BAR_LGKM();                               // all waves done reading prev tile
      *(bf16x8*)&Ks2[0][lr][lc]     = kr0;
      *(bf16x8*)&Ks2[0][lr][lc + 8] = kr1;
      *(bf16x8*)&Vs[lr][lc]     = vr0;
      *(bf16x8*)&Vs[lr][lc + 8] = vr1;
      BAR_LGKM();                               // stage visible
      if (jt + 1 < NT) {                        // loads issued BEFORE this tile's stores
        const bf16* p = kst + (size_t)(jt + 1) * 64 * QKVN;
        kr0 = *(const bf16x8*)(p);
        kr1 = *(const bf16x8*)(p + 8);
        p = vst + (size_t)(jt + 1) * 64;
        vr0 = *(const bf16x8*)(p);
        vr1 = *(const bf16x8*)(p + 8);
      }
      // ---- HI stripe (always) ----
      {
        f32x4 acc[4] = {};
#pragma unroll
        for (int nn = 0; nn < 4; ++nn) {
          bf16x8 bk0 = *(const bf16x8*)&Ks2[0][nn*16 + fr][fg*8];
          bf16x8 bk1 = *(const bf16x8*)&Ks2[0][nn*16 + fr][32 + fg*8];
          acc[nn] = __builtin_amdgcn_mfma_f32_16x16x32_bf16(bk0, aqH[0], acc[nn], 0, 0, 0);
          acc[nn] = __builtin_amdgcn_mfma_f32_16x16x32_bf16(bk1, aqH[1], acc[nn], 0, 0, 0);
        }
        const bool diag = (jt == NT - 1);
#pragma unroll
        for (int nn = 0; nn < 4; ++nn) {
          f32x4 pv;
          bf16x4 pb;
#pragma unroll
          for (int r = 0; r < 4; ++r) {
            float e = __expf(acc[nn][r] * 0.125f) * rsH;
            pv[r] = (diag && (nn * 16 + cb + r > thr)) ? 0.f : e;
            pb[r] = (bf16)pv[r];
          }
          *(f32x4*)&awpH[j0 + nn * 16 + cb] = pv;   // plain cached store
          *(bf16x4*)&Ps[wave][fr][nn * 16 + cb] = pb;
        }
        bf16x8 pa0 = *(const bf16x8*)&Ps[wave][fr][fg * 8];
        bf16x8 pa1 = *(const bf16x8*)&Ps[wave][fr][32 + fg * 8];
#pragma unroll
        for (int nn = 0; nn < 4; ++nn) {
          bf16x8 bv0 = *(const bf16x8*)&Vs[nn*16 + fr][fg*8];
          bf16x8 bv1 = *(const bf16x8*)&Vs[nn*16 + fr][32 + fg*8];
          oH[nn] = __builtin_amdgcn_mfma_f32_16x16x32_bf16(pa0, bv0, oH[nn], 0, 0, 0);
          oH[nn] = __builtin_amdgcn_mfma_f32_16x16x32_bf16(pa1, bv1, oH[nn], 0, 0, 0);
        }
      }
      // ---- LO stripe (jt <= qt; block-uniform) ----
      if (jt <= qt) {
        f32x4 acc[4] = {};
#pragma unroll
        for (int nn = 0; nn < 4; ++nn) {
          bf16x8 bk0 = *(const bf16x8*)&Ks2[0][nn*16 + fr][fg*8];
          bf16x8 bk1 = *(const bf16x8*)&Ks2[0][nn*16 + fr][32 + fg*8];
          acc[nn] = __builtin_amdgcn_mfma_f32_16x16x32_bf16(bk0, aqL[0], acc[nn], 0, 0, 0);
          acc[nn] = __builtin_amdgcn_mfma_f32_16x16x32_bf16(bk1, aqL[1], acc[nn], 0, 0, 0);
        }
        const bool diag = (jt == qt);
#pragma unroll
        for (int nn = 0; nn < 4; ++nn) {
          f32x4 pv;
          bf16x4 pb;
#pragma unroll
          for (int r = 0; r < 4; ++r) {
            float e = __expf(acc[nn][r] * 0.125f) * rsL;
            pv[r] = (diag && (nn * 16 + cb + r > thr)) ? 0.f : e;
            pb[r] = (bf16)pv[r];
          }
          *(f32x4*)&awpL[j0 + nn * 16 + cb] = pv;   // plain cached store
          *(bf16x4*)&Ps[wave][fr][nn * 16 + cb] = pb;
        }
        bf16x8 pa0 = *(const bf16x8*)&Ps[wave][fr][fg * 8];
        bf16x8 pa1 = *(const bf16x8*)&Ps[wave][fr][32 + fg * 8];
#pragma unroll
        for (int nn = 0; nn < 4; ++nn) {
          bf16x8 bv0 = *(const bf16x8*)&Vs[nn*16 + fr][fg*8];
          bf16x8 bv1 = *(const bf16x8*)&Vs[nn*16 + fr][32 + fg*8];
          oL[nn] = __builtin_amdgcn_mfma_f32_16x16x32_bf16(pa0, bv0, oL[nn], 0, 0, 0);
          oL[nn] = __builtin_amdgcn_mfma_f32_16x16x32_bf16(pa1, bv1, oL[nn], 0, 0, 0);
        }
      }
    }
  }

  // attn_out (bf16) for both stripes (PV D-layout: row q = rt+r, col d = nn*16+fr)
#pragma unroll
  for (int nn = 0; nn < 4; ++nn)
#pragma unroll
    for (int r = 0; r < 4; ++r) {
      int rowL = qLo + rt + r;
      int rowH = qHi + rt + r;
      attn_out[(size_t)(b * S_ + rowL) * (NH_*HD_) + h * 64 + nn * 16 + fr] = (bf16)oL[nn][r];
      attn_out[(size_t)(b * S_ + rowH) * (NH_*HD_) + h * 64 + nn * 16 + fr] = (bf16)oH[nn][r];
    }
}

// ---------------------------------------------------------------------------
extern "C" void kernel_launch(void* const* d_in, const int* in_sizes, int n_in,
                              void* d_out, int out_size, void* d_ws, size_t ws_size,
                              hipStream_t stream) {
  const float* hs   = (const float*)d_in[0];
  const float* cosp = (const float*)d_in[1];
  const float* sinp = (const float*)d_in[2];
  // d_in[3] = attention_mask (causal; applied analytically)
  const float* Wq = (const float*)d_in[4];
  const float* Wk = (const float*)d_in[5];
  const float* Wv = (const float*)d_in[6];
  const float* Wo = (const float*)d_in[7];

  char* ws = (char*)d_ws;
  bf16* hs_b   = (bf16*)(ws);                   // 16 MB
  bf16* qkv_b  = (bf16*)(ws + (16u << 20));     // 24 MB (TOK x 3072)
  bf16* vT_b   = (bf16*)(ws + (40u << 20));     // 4 MB
  bf16* ao_b   = (bf16*)(ws + (44u << 20));     // 16 MB
  bf16* Wqkv_b = (bf16*)(ws + (60u << 20));     // 12 MB (3072 x 2048)
  bf16* Wo_b   = (bf16*)(ws + (72u << 20));     // 8 MB

  float* outp  = (float*)d_out;
  float* attnw = outp + (size_t)TOK_ * HID_;    // + 8388608

  // casts to bf16
  cast_f32_bf16<<<(TOK_*HID_/4 + 255)/256, 256, 0, stream>>>(hs, hs_b, TOK_*HID_/4);
  cast_wqkv<<<(1572864 + 255)/256, 256, 0, stream>>>(Wq, Wk, Wv, Wqkv_b);
  cast_f32_bf16<<<(HID_*NH_*HD_/4 + 255)/256, 256, 0, stream>>>(Wo, Wo_b, HID_*NH_*HD_/4);

  // fused QKV projection: (TOK,2048) @ (3072,2048)^T -> (TOK,3072)
  gemm256<false><<<dim3(QKVN/256, TOK_/256), 512, 0, stream>>>(hs_b, Wqkv_b, qkv_b, TOK_, QKVN, HID_);

  // RoPE (in place, one block per token)
  rope_fused<<<TOK_, 256, 0, stream>>>(qkv_b, cosp, sinp);

  // V transpose for PV B-operand contiguity
  transpose_v<<<dim3(S_/64, B_*NKV_), 256, 0, stream>>>(qkv_b + 2560, vT_b);

  // fused attention (stripe-paired; writes attn_weights f32 + attn_out bf16)
  attn_kernel<<<dim3(S_/128, B_*NH_), 256, 0, stream>>>(qkv_b, vT_b, attnw, ao_b);

  // output projection (f32 out)
  gemm256<true><<<dim3(HID_/256, TOK_/256), 512, 0, stream>>>(ao_b, Wo_b, outp, TOK_, HID_, HID_);
}